// Round 1
// baseline (701.299 us; speedup 1.0000x reference)
//
#include <hip/hip_runtime.h>
#include <math.h>

#define BB 64
#define PP 100
#define NN 1000
#define DD 128
#define HH 8
#define QDQ 16
#define NTOT 1196
#define HALFK 598

// ---------------- Kernel A: q = q_first + x @ Wq^T  (layout B,H,P,16) ----------------
__global__ __launch_bounds__(128) void k_qcalc(const float* __restrict__ x,
                                               const float* __restrict__ Wq,
                                               const float* __restrict__ qf,
                                               float* __restrict__ qout) {
  int bp = blockIdx.x; int b = bp / PP, p = bp % PP;
  int t = threadIdx.x;
  __shared__ float xs[DD];
  xs[t] = x[(size_t)bp * DD + t];
  __syncthreads();
  const float* wrow = Wq + (size_t)t * DD;
  float acc = 0.f;
#pragma unroll 8
  for (int d = 0; d < DD; d += 4) {
    float4 w4 = *(const float4*)(wrow + d);
    acc += xs[d] * w4.x + xs[d + 1] * w4.y + xs[d + 2] * w4.z + xs[d + 3] * w4.w;
  }
  int h = t >> 4, qd = t & 15;
  size_t qi = ((size_t)(b * HH + h) * PP + p) * QDQ + qd;
  qout[qi] = acc + qf[qi];
}

// ---------------- Kernel F: mask transpose (B,P,N) -> (B,N,P) ----------------
__global__ __launch_bounds__(256) void k_mask_t(const float* __restrict__ mask,
                                                float* __restrict__ mt) {
  size_t i = (size_t)blockIdx.x * blockDim.x + threadIdx.x;
  if (i >= (size_t)BB * NN * PP) return;
  int p = (int)(i % PP);
  size_t bn = i / PP;
  int n = (int)(bn % NN);
  int b = (int)(bn / NN);
  mt[i] = mask[((size_t)b * PP + p) * NN + n];
}

// ---------------- Kernel B: MHA partial (lane-per-query, online softmax) ----------------
// grid = 512 (b,h) * 2 key-halves; block = 128 threads (lane = query p)
__global__ __launch_bounds__(128) void k_mha(const float* __restrict__ kk,
                                             const float* __restrict__ vv,
                                             const float* __restrict__ qws,
                                             const float* __restrict__ mt,
                                             float* __restrict__ part) {
  int bh = blockIdx.x >> 1, half = blockIdx.x & 1;
  int b = bh >> 3;
  int p = threadIdx.x;
  int pc = p < PP ? p : PP - 1;  // clamp reads for inactive lanes

  float q[QDQ];
#pragma unroll
  for (int j = 0; j < QDQ; ++j)
    q[j] = qws[((size_t)bh * PP + pc) * QDQ + j] * 0.25f;  // fold 1/sqrt(16)

  float acc[QDQ];
#pragma unroll
  for (int j = 0; j < QDQ; ++j) acc[j] = 0.f;
  float m = -1e30f, l = 0.f;

  const float* kg = kk + ((size_t)bh * NTOT + (size_t)half * HALFK) * QDQ;
  const float* vg = vv + ((size_t)bh * NTOT + (size_t)half * HALFK) * QDQ;
  const float* mtb = mt + (size_t)b * NN * PP;
  int n0 = half * HALFK;

  for (int i = 0; i < HALFK; ++i) {
    const float4 k0 = *(const float4*)(kg + i * QDQ);
    const float4 k1 = *(const float4*)(kg + i * QDQ + 4);
    const float4 k2 = *(const float4*)(kg + i * QDQ + 8);
    const float4 k3 = *(const float4*)(kg + i * QDQ + 12);
    float s = q[0] * k0.x + q[1] * k0.y + q[2] * k0.z + q[3] * k0.w
            + q[4] * k1.x + q[5] * k1.y + q[6] * k1.z + q[7] * k1.w
            + q[8] * k2.x + q[9] * k2.y + q[10] * k2.z + q[11] * k2.w
            + q[12] * k3.x + q[13] * k3.y + q[14] * k3.z + q[15] * k3.w;
    int n = n0 + i;
    if (n < NN) s += mtb[(size_t)n * PP + pc];  // coalesced via transposed mask

    if (s > m + 8.f) {  // deferred-max rescale (rare)
      float c = __expf(m - s);
      l *= c;
#pragma unroll
      for (int j = 0; j < QDQ; ++j) acc[j] *= c;
      m = s;
    }
    float w = __expf(s - m);
    l += w;
    const float4 v0 = *(const float4*)(vg + i * QDQ);
    const float4 v1 = *(const float4*)(vg + i * QDQ + 4);
    const float4 v2 = *(const float4*)(vg + i * QDQ + 8);
    const float4 v3 = *(const float4*)(vg + i * QDQ + 12);
    acc[0] += w * v0.x;  acc[1] += w * v0.y;  acc[2] += w * v0.z;  acc[3] += w * v0.w;
    acc[4] += w * v1.x;  acc[5] += w * v1.y;  acc[6] += w * v1.z;  acc[7] += w * v1.w;
    acc[8] += w * v2.x;  acc[9] += w * v2.y;  acc[10] += w * v2.z; acc[11] += w * v2.w;
    acc[12] += w * v3.x; acc[13] += w * v3.y; acc[14] += w * v3.z; acc[15] += w * v3.w;
  }

  if (p < PP) {
    float* o = part + ((size_t)blockIdx.x * PP + p) * 18;
#pragma unroll
    for (int j = 0; j < QDQ; ++j) o[j] = acc[j];
    o[16] = m;
    o[17] = l;
  }
}

// ---------------- Kernel C': merge halves + mh_combine ----------------
__global__ __launch_bounds__(128) void k_merge_combine(const float* __restrict__ part,
                                                       const float* __restrict__ MC,
                                                       float* __restrict__ mh) {
  int bp = blockIdx.x; int b = bp / PP, p = bp % PP;
  int t = threadIdx.x; int h = t >> 4, qd = t & 15;
  __shared__ float oc[DD];
  int bh = b * HH + h;
  const float* p0 = part + ((size_t)(bh * 2 + 0) * PP + p) * 18;
  const float* p1 = part + ((size_t)(bh * 2 + 1) * PP + p) * 18;
  float m0 = p0[16], l0 = p0[17], m1 = p1[16], l1 = p1[17];
  float M = fmaxf(m0, m1);
  float c0 = __expf(m0 - M), c1 = __expf(m1 - M);
  float L = l0 * c0 + l1 * c1;
  oc[t] = (p0[qd] * c0 + p1[qd] * c1) / L;
  __syncthreads();
  const float* mcrow = MC + (size_t)t * DD;
  float a = 0.f;
#pragma unroll 8
  for (int i = 0; i < DD; i += 4) {
    float4 w4 = *(const float4*)(mcrow + i);
    a += oc[i] * w4.x + oc[i + 1] * w4.y + oc[i + 2] * w4.z + oc[i + 3] * w4.w;
  }
  mh[(size_t)bp * DD + t] = a;
}

// ---------------- Kernel D: score2[b,p,n] = sum_d mh[b,p,d]*shk[b,d,n] ----------------
// grid = 64 b * 16 n-tiles(64); block 256 = 32 n-lanes * 8 p-groups; 2n x 13p regs/thread
__global__ __launch_bounds__(256) void k_score2(const float* __restrict__ mh,
                                                const float* __restrict__ shk,
                                                float* __restrict__ sc) {
  int blk = blockIdx.x; int b = blk >> 4, nt = blk & 15;
  int tid = threadIdx.x; int nl = tid & 31, pg = tid >> 5;
  __shared__ float A[PP * 132];
  for (int idx = tid; idx < PP * DD; idx += 256)
    A[(idx >> 7) * 132 + (idx & 127)] = mh[(size_t)b * PP * DD + idx];
  __syncthreads();

  int na = nt * 64 + nl, nb2 = na + 32;
  int nca = na < NN ? na : NN - 1, ncb = nb2 < NN ? nb2 : NN - 1;
  const float* S = shk + (size_t)b * DD * NN;
  float acc0[13], acc1[13];
#pragma unroll
  for (int i = 0; i < 13; ++i) { acc0[i] = 0.f; acc1[i] = 0.f; }

  for (int d = 0; d < DD; d += 4) {
    float sa0 = S[(size_t)(d + 0) * NN + nca];
    float sa1 = S[(size_t)(d + 1) * NN + nca];
    float sa2 = S[(size_t)(d + 2) * NN + nca];
    float sa3 = S[(size_t)(d + 3) * NN + nca];
    float sb0 = S[(size_t)(d + 0) * NN + ncb];
    float sb1 = S[(size_t)(d + 1) * NN + ncb];
    float sb2 = S[(size_t)(d + 2) * NN + ncb];
    float sb3 = S[(size_t)(d + 3) * NN + ncb];
#pragma unroll
    for (int i = 0; i < 13; ++i) {
      int p = pg + (i << 3);
      if (p < PP) {
        const float4 a4 = *(const float4*)&A[p * 132 + d];
        acc0[i] += a4.x * sa0 + a4.y * sa1 + a4.z * sa2 + a4.w * sa3;
        acc1[i] += a4.x * sb0 + a4.y * sb1 + a4.z * sb2 + a4.w * sb3;
      }
    }
  }
#pragma unroll
  for (int i = 0; i < 13; ++i) {
    int p = pg + (i << 3);
    if (p < PP) {
      size_t base = ((size_t)b * PP + p) * NN;
      if (na < NN) sc[base + na] = acc0[i];
      if (nb2 < NN) sc[base + nb2] = acc1[i];
    }
  }
}

// ---------------- Kernel E: tanh clip + edge bias gather + mask + row softmax ----------------
__global__ __launch_bounds__(256) void k_finsm(const float* __restrict__ sc,
                                               const float* __restrict__ eb,
                                               const int* __restrict__ cn,
                                               const float* __restrict__ mask,
                                               float* __restrict__ out) {
  int bp = blockIdx.x; int b = bp / PP;
  int t = threadIdx.x;
  int node = cn[bp];
  const float* scp = sc + (size_t)bp * NN;
  const float* ebp = eb + ((size_t)b * NN + node) * NN;
  const float* mp = mask + (size_t)bp * NN;
  const float inv_sqrtD = 0.08838834764831845f;  // 1/sqrt(128)

  float vals[4];
  float m = -1e30f;
#pragma unroll
  for (int i = 0; i < 4; ++i) {
    int n = t + (i << 8);
    if (n < NN) {
      float lg = 10.f * tanhf(scp[n] * inv_sqrtD) + ebp[n] + mp[n];
      vals[i] = lg;
      m = fmaxf(m, lg);
    } else {
      vals[i] = -1e30f;
    }
  }
#pragma unroll
  for (int off = 32; off; off >>= 1) m = fmaxf(m, __shfl_xor(m, off));
  __shared__ float red[4];
  int w = t >> 6, lane = t & 63;
  if (lane == 0) red[w] = m;
  __syncthreads();
  m = fmaxf(fmaxf(red[0], red[1]), fmaxf(red[2], red[3]));
  __syncthreads();

  float s = 0.f;
#pragma unroll
  for (int i = 0; i < 4; ++i) {
    int n = t + (i << 8);
    float e = (n < NN) ? __expf(vals[i] - m) : 0.f;
    vals[i] = e;
    s += e;
  }
#pragma unroll
  for (int off = 32; off; off >>= 1) s += __shfl_xor(s, off);
  if (lane == 0) red[w] = s;
  __syncthreads();
  s = red[0] + red[1] + red[2] + red[3];
  float inv = 1.f / s;
#pragma unroll
  for (int i = 0; i < 4; ++i) {
    int n = t + (i << 8);
    if (n < NN) out[(size_t)bp * NN + n] = vals[i] * inv;
  }
}

extern "C" void kernel_launch(void* const* d_in, const int* in_sizes, int n_in,
                              void* d_out, int out_size, void* d_ws, size_t ws_size,
                              hipStream_t stream) {
  const float* x    = (const float*)d_in[0];   // encoded_last_node (B,P,D)
  const float* mask = (const float*)d_in[1];   // ninf_mask (B,P,N)
  const float* qf   = (const float*)d_in[2];   // q_first (B,H,P,QD)
  const float* kk   = (const float*)d_in[3];   // k (B,H,NTOT,QD)
  const float* vv   = (const float*)d_in[4];   // v (B,H,NTOT,QD)
  const float* shk  = (const float*)d_in[5];   // single_head_key (B,D,N)
  const float* Wq   = (const float*)d_in[6];   // (128,128)
  const float* MC   = (const float*)d_in[7];   // (128,128)
  const float* eb   = (const float*)d_in[8];   // edge_bias (B,N,N)
  const int*   cn   = (const int*)d_in[9];     // current_node (B,P)

  float* out = (float*)d_out;
  float* ws = (float*)d_ws;
  float* q_ws = ws;                                   // 819,200 f
  float* part = ws + 819200;                          // 1,843,200 f
  float* mh   = ws + 819200 + 1843200;                // 819,200 f
  float* mt   = ws + 819200 + 1843200 + 819200;       // 6,400,000 f (mask_t)
  float* sc   = mt;  // score2 overlays mask_t (written only after last mask_t read)

  hipLaunchKernelGGL(k_qcalc, dim3(BB * PP), dim3(128), 0, stream, x, Wq, qf, q_ws);
  hipLaunchKernelGGL(k_mask_t, dim3(25000), dim3(256), 0, stream, mask, mt);
  hipLaunchKernelGGL(k_mha, dim3(1024), dim3(128), 0, stream, kk, vv, q_ws, mt, part);
  hipLaunchKernelGGL(k_merge_combine, dim3(BB * PP), dim3(128), 0, stream, part, MC, mh);
  hipLaunchKernelGGL(k_score2, dim3(1024), dim3(256), 0, stream, mh, shk, sc);
  hipLaunchKernelGGL(k_finsm, dim3(BB * PP), dim3(256), 0, stream, sc, eb, cn, mask, out);
}

// Round 2
// 308.397 us; speedup vs baseline: 2.2740x; 2.2740x over previous
//
#include <hip/hip_runtime.h>
#include <math.h>

#define BB 64
#define PP 100
#define NN 1000
#define DD 128
#define HH 8
#define QDQ 16
#define NTOT 1196
#define HALFK 598
#define CHUNK 256

// ---------------- Kernel A: q = q_first + x @ Wq^T  (layout B,H,P,16) ----------------
__global__ __launch_bounds__(128) void k_qcalc(const float* __restrict__ x,
                                               const float* __restrict__ Wq,
                                               const float* __restrict__ qf,
                                               float* __restrict__ qout) {
  int bp = blockIdx.x; int b = bp / PP, p = bp % PP;
  int t = threadIdx.x;
  __shared__ float xs[DD];
  xs[t] = x[(size_t)bp * DD + t];
  __syncthreads();
  const float* wrow = Wq + (size_t)t * DD;
  float acc = 0.f;
#pragma unroll 8
  for (int d = 0; d < DD; d += 4) {
    float4 w4 = *(const float4*)(wrow + d);
    acc += xs[d] * w4.x + xs[d + 1] * w4.y + xs[d + 2] * w4.z + xs[d + 3] * w4.w;
  }
  int h = t >> 4, qd = t & 15;
  size_t qi = ((size_t)(b * HH + h) * PP + p) * QDQ + qd;
  qout[qi] = acc + qf[qi];
}

// ---------------- Kernel F: tiled mask transpose (B,P,N) -> (B,N,P) ----------------
__global__ __launch_bounds__(256) void k_mask_t(const float* __restrict__ mask,
                                                float* __restrict__ mt) {
  __shared__ float tile[64][65];
  int nt = blockIdx.x;           // 16 tiles over n (0..1023, bound 1000)
  int pt = blockIdx.y;           // 2 tiles over p (0..127, bound 100)
  int b  = blockIdx.z;
  int tx = threadIdx.x & 63, ty = threadIdx.x >> 6;
  int n0 = nt * 64, p0 = pt * 64;
#pragma unroll
  for (int r = ty; r < 64; r += 4) {
    int p = p0 + r, n = n0 + tx;
    tile[r][tx] = (p < PP && n < NN) ? mask[((size_t)b * PP + p) * NN + n] : 0.f;
  }
  __syncthreads();
#pragma unroll
  for (int r = ty; r < 64; r += 4) {
    int n = n0 + r, p = p0 + tx;
    if (n < NN && p < PP) mt[((size_t)b * NN + n) * PP + p] = tile[tx][r];
  }
}

// ---------------- Kernel B: MHA partial, LDS-staged k/v ----------------
// grid = 512 bh * 2 key-halves; block = 512 (4 query-groups of 128, lane=query)
// keys of this half staged to LDS in 256-key chunks; groups interleave mod 4;
// 4-way online-softmax merge in LDS -> one part record per (block, p).
__global__ __launch_bounds__(512) void k_mha(const float* __restrict__ kk,
                                             const float* __restrict__ vv,
                                             const float* __restrict__ qws,
                                             const float* __restrict__ mt,
                                             float* __restrict__ part) {
  int bh = blockIdx.x >> 1, half = blockIdx.x & 1;
  int b = bh >> 3;
  int tid = threadIdx.x;
  int g = tid >> 7;          // query-group 0..3
  int p = tid & 127;         // lane-query
  int pc = p < PP ? p : PP - 1;

  __shared__ __align__(16) float smem[8192];   // 32 KB: k 16KB | v 16KB ; reused for merge
  float4* s4 = (float4*)smem;                  // k: s4[0..1023], v: s4[1024..2047]

  float q[QDQ];
  const float* qrow = qws + ((size_t)bh * PP + pc) * QDQ;
#pragma unroll
  for (int j = 0; j < QDQ; j += 4) {
    float4 q4 = *(const float4*)(qrow + j);
    q[j] = q4.x * 0.25f; q[j + 1] = q4.y * 0.25f;
    q[j + 2] = q4.z * 0.25f; q[j + 3] = q4.w * 0.25f;
  }

  float acc[QDQ];
#pragma unroll
  for (int j = 0; j < QDQ; ++j) acc[j] = 0.f;
  float m = -1e30f, l = 0.f;

  const float4* kg4 = (const float4*)(kk + (size_t)bh * NTOT * QDQ);
  const float4* vg4 = (const float4*)(vv + (size_t)bh * NTOT * QDQ);
  const float* mtb = mt + (size_t)b * NN * PP;
  int key0 = half * HALFK;

  for (int c = 0; c < 3; ++c) {                 // 598 = 256 + 256 + 86
    int base = c * CHUNK;
    int L = HALFK - base; if (L > CHUNK) L = CHUNK;
    __syncthreads();
    int nf4 = L * 4;
    for (int idx = tid; idx < nf4; idx += 512) {
      s4[idx]        = kg4[(size_t)(key0 + base) * 4 + idx];
      s4[1024 + idx] = vg4[(size_t)(key0 + base) * 4 + idx];
    }
    __syncthreads();
#pragma unroll 2
    for (int i = g; i < L; i += 4) {
      int n = key0 + base + i;
      float mk = (n < NN) ? mtb[(size_t)n * PP + pc] : 0.f;
      float4 k0 = s4[i * 4 + 0], k1 = s4[i * 4 + 1];
      float4 k2 = s4[i * 4 + 2], k3 = s4[i * 4 + 3];
      float sA = q[0] * k0.x + q[1] * k0.y + q[2] * k0.z + q[3] * k0.w;
      float sB = q[4] * k1.x + q[5] * k1.y + q[6] * k1.z + q[7] * k1.w;
      float sC = q[8] * k2.x + q[9] * k2.y + q[10] * k2.z + q[11] * k2.w;
      float sD = q[12] * k3.x + q[13] * k3.y + q[14] * k3.z + q[15] * k3.w;
      float s = (sA + sB) + (sC + sD) + mk;

      if (s > m + 8.f) {                        // deferred-max rescale (rare)
        float cc = __expf(m - s);
        l *= cc;
#pragma unroll
        for (int j = 0; j < QDQ; ++j) acc[j] *= cc;
        m = s;
      }
      float w = __expf(s - m);
      l += w;
      float4 v0 = s4[1024 + i * 4 + 0], v1 = s4[1024 + i * 4 + 1];
      float4 v2 = s4[1024 + i * 4 + 2], v3 = s4[1024 + i * 4 + 3];
      acc[0] += w * v0.x;  acc[1] += w * v0.y;  acc[2] += w * v0.z;  acc[3] += w * v0.w;
      acc[4] += w * v1.x;  acc[5] += w * v1.y;  acc[6] += w * v1.z;  acc[7] += w * v1.w;
      acc[8] += w * v2.x;  acc[9] += w * v2.y;  acc[10] += w * v2.z; acc[11] += w * v2.w;
      acc[12] += w * v3.x; acc[13] += w * v3.y; acc[14] += w * v3.z; acc[15] += w * v3.w;
    }
  }

  __syncthreads();                              // all compute done; reuse smem
  if (p < PP) {
    float* pl = smem + ((size_t)(g * PP + p)) * 18;
#pragma unroll
    for (int j = 0; j < QDQ; ++j) pl[j] = acc[j];
    pl[16] = m;
    pl[17] = l;
  }
  __syncthreads();
  // 4-way merge -> unnormalized (A[16], M, L) per p, matching part-record format
  for (int idx = tid; idx < PP * QDQ; idx += 512) {
    int pp2 = idx >> 4, qd = idx & 15;
    float m0 = smem[(0 * PP + pp2) * 18 + 16], l0 = smem[(0 * PP + pp2) * 18 + 17];
    float m1 = smem[(1 * PP + pp2) * 18 + 16], l1 = smem[(1 * PP + pp2) * 18 + 17];
    float m2 = smem[(2 * PP + pp2) * 18 + 16], l2 = smem[(2 * PP + pp2) * 18 + 17];
    float m3 = smem[(3 * PP + pp2) * 18 + 16], l3 = smem[(3 * PP + pp2) * 18 + 17];
    float M = fmaxf(fmaxf(m0, m1), fmaxf(m2, m3));
    float c0 = __expf(m0 - M), c1 = __expf(m1 - M);
    float c2 = __expf(m2 - M), c3 = __expf(m3 - M);
    float A = smem[(0 * PP + pp2) * 18 + qd] * c0 + smem[(1 * PP + pp2) * 18 + qd] * c1
            + smem[(2 * PP + pp2) * 18 + qd] * c2 + smem[(3 * PP + pp2) * 18 + qd] * c3;
    float* o = part + ((size_t)blockIdx.x * PP + pp2) * 18;
    o[qd] = A;
    if (qd == 0) {
      o[16] = M;
      o[17] = l0 * c0 + l1 * c1 + l2 * c2 + l3 * c3;
    }
  }
}

// ---------------- Kernel C': merge halves + mh_combine ----------------
__global__ __launch_bounds__(128) void k_merge_combine(const float* __restrict__ part,
                                                       const float* __restrict__ MC,
                                                       float* __restrict__ mh) {
  int bp = blockIdx.x; int b = bp / PP, p = bp % PP;
  int t = threadIdx.x; int h = t >> 4, qd = t & 15;
  __shared__ float oc[DD];
  int bh = b * HH + h;
  const float* p0 = part + ((size_t)(bh * 2 + 0) * PP + p) * 18;
  const float* p1 = part + ((size_t)(bh * 2 + 1) * PP + p) * 18;
  float m0 = p0[16], l0 = p0[17], m1 = p1[16], l1 = p1[17];
  float M = fmaxf(m0, m1);
  float c0 = __expf(m0 - M), c1 = __expf(m1 - M);
  float L = l0 * c0 + l1 * c1;
  oc[t] = (p0[qd] * c0 + p1[qd] * c1) / L;
  __syncthreads();
  const float* mcrow = MC + (size_t)t * DD;
  float a = 0.f;
#pragma unroll 8
  for (int i = 0; i < DD; i += 4) {
    float4 w4 = *(const float4*)(mcrow + i);
    a += oc[i] * w4.x + oc[i + 1] * w4.y + oc[i + 2] * w4.z + oc[i + 3] * w4.w;
  }
  mh[(size_t)bp * DD + t] = a;
}

// ---------------- Kernel D: score2[b,p,n] = sum_d mh[b,p,d]*shk[b,d,n] ----------------
__global__ __launch_bounds__(256) void k_score2(const float* __restrict__ mh,
                                                const float* __restrict__ shk,
                                                float* __restrict__ sc) {
  int blk = blockIdx.x; int b = blk >> 4, nt = blk & 15;
  int tid = threadIdx.x; int nl = tid & 31, pg = tid >> 5;
  __shared__ float A[PP * 132];
  for (int idx = tid; idx < PP * DD; idx += 256)
    A[(idx >> 7) * 132 + (idx & 127)] = mh[(size_t)b * PP * DD + idx];
  __syncthreads();

  int na = nt * 64 + nl, nb2 = na + 32;
  int nca = na < NN ? na : NN - 1, ncb = nb2 < NN ? nb2 : NN - 1;
  const float* S = shk + (size_t)b * DD * NN;
  float acc0[13], acc1[13];
#pragma unroll
  for (int i = 0; i < 13; ++i) { acc0[i] = 0.f; acc1[i] = 0.f; }

  for (int d = 0; d < DD; d += 4) {
    float sa0 = S[(size_t)(d + 0) * NN + nca];
    float sa1 = S[(size_t)(d + 1) * NN + nca];
    float sa2 = S[(size_t)(d + 2) * NN + nca];
    float sa3 = S[(size_t)(d + 3) * NN + nca];
    float sb0 = S[(size_t)(d + 0) * NN + ncb];
    float sb1 = S[(size_t)(d + 1) * NN + ncb];
    float sb2 = S[(size_t)(d + 2) * NN + ncb];
    float sb3 = S[(size_t)(d + 3) * NN + ncb];
#pragma unroll
    for (int i = 0; i < 13; ++i) {
      int p = pg + (i << 3);
      if (p < PP) {
        const float4 a4 = *(const float4*)&A[p * 132 + d];
        acc0[i] += a4.x * sa0 + a4.y * sa1 + a4.z * sa2 + a4.w * sa3;
        acc1[i] += a4.x * sb0 + a4.y * sb1 + a4.z * sb2 + a4.w * sb3;
      }
    }
  }
#pragma unroll
  for (int i = 0; i < 13; ++i) {
    int p = pg + (i << 3);
    if (p < PP) {
      size_t base = ((size_t)b * PP + p) * NN;
      if (na < NN) sc[base + na] = acc0[i];
      if (nb2 < NN) sc[base + nb2] = acc1[i];
    }
  }
}

// ---------------- Kernel E: tanh clip + edge bias gather + mask + row softmax ----------------
__global__ __launch_bounds__(256) void k_finsm(const float* __restrict__ sc,
                                               const float* __restrict__ eb,
                                               const int* __restrict__ cn,
                                               const float* __restrict__ mask,
                                               float* __restrict__ out) {
  int bp = blockIdx.x; int b = bp / PP;
  int t = threadIdx.x;
  int node = cn[bp];
  const float* scp = sc + (size_t)bp * NN;
  const float* ebp = eb + ((size_t)b * NN + node) * NN;
  const float* mp = mask + (size_t)bp * NN;
  const float inv_sqrtD = 0.08838834764831845f;  // 1/sqrt(128)

  float vals[4];
  float m = -1e30f;
#pragma unroll
  for (int i = 0; i < 4; ++i) {
    int n = t + (i << 8);
    if (n < NN) {
      float lg = 10.f * tanhf(scp[n] * inv_sqrtD) + ebp[n] + mp[n];
      vals[i] = lg;
      m = fmaxf(m, lg);
    } else {
      vals[i] = -1e30f;
    }
  }
#pragma unroll
  for (int off = 32; off; off >>= 1) m = fmaxf(m, __shfl_xor(m, off));
  __shared__ float red[4];
  int w = t >> 6, lane = t & 63;
  if (lane == 0) red[w] = m;
  __syncthreads();
  m = fmaxf(fmaxf(red[0], red[1]), fmaxf(red[2], red[3]));
  __syncthreads();

  float s = 0.f;
#pragma unroll
  for (int i = 0; i < 4; ++i) {
    int n = t + (i << 8);
    float e = (n < NN) ? __expf(vals[i] - m) : 0.f;
    vals[i] = e;
    s += e;
  }
#pragma unroll
  for (int off = 32; off; off >>= 1) s += __shfl_xor(s, off);
  if (lane == 0) red[w] = s;
  __syncthreads();
  s = red[0] + red[1] + red[2] + red[3];
  float inv = 1.f / s;
#pragma unroll
  for (int i = 0; i < 4; ++i) {
    int n = t + (i << 8);
    if (n < NN) out[(size_t)bp * NN + n] = vals[i] * inv;
  }
}

extern "C" void kernel_launch(void* const* d_in, const int* in_sizes, int n_in,
                              void* d_out, int out_size, void* d_ws, size_t ws_size,
                              hipStream_t stream) {
  const float* x    = (const float*)d_in[0];   // encoded_last_node (B,P,D)
  const float* mask = (const float*)d_in[1];   // ninf_mask (B,P,N)
  const float* qf   = (const float*)d_in[2];   // q_first (B,H,P,QD)
  const float* kk   = (const float*)d_in[3];   // k (B,H,NTOT,QD)
  const float* vv   = (const float*)d_in[4];   // v (B,H,NTOT,QD)
  const float* shk  = (const float*)d_in[5];   // single_head_key (B,D,N)
  const float* Wq   = (const float*)d_in[6];   // (128,128)
  const float* MC   = (const float*)d_in[7];   // (128,128)
  const float* eb   = (const float*)d_in[8];   // edge_bias (B,N,N)
  const int*   cn   = (const int*)d_in[9];     // current_node (B,P)

  float* out = (float*)d_out;
  float* ws = (float*)d_ws;
  float* q_ws = ws;                                   // 819,200 f
  float* part = ws + 819200;                          // 1,843,200 f
  float* mh   = ws + 819200 + 1843200;                // 819,200 f
  float* mt   = ws + 819200 + 1843200 + 819200;       // 6,400,000 f (mask_t)
  float* sc   = mt;  // score2 overlays mask_t (written only after last mask_t read)

  hipLaunchKernelGGL(k_qcalc, dim3(BB * PP), dim3(128), 0, stream, x, Wq, qf, q_ws);
  hipLaunchKernelGGL(k_mask_t, dim3(16, 2, BB), dim3(256), 0, stream, mask, mt);
  hipLaunchKernelGGL(k_mha, dim3(1024), dim3(512), 0, stream, kk, vv, q_ws, mt, part);
  hipLaunchKernelGGL(k_merge_combine, dim3(BB * PP), dim3(128), 0, stream, part, MC, mh);
  hipLaunchKernelGGL(k_score2, dim3(1024), dim3(256), 0, stream, mh, shk, sc);
  hipLaunchKernelGGL(k_finsm, dim3(BB * PP), dim3(256), 0, stream, sc, eb, cn, mask, out);
}

// Round 3
// 253.220 us; speedup vs baseline: 2.7695x; 1.2179x over previous
//
#include <hip/hip_runtime.h>
#include <math.h>

#define BB 64
#define PP 100
#define NN 1000
#define DD 128
#define HH 8
#define QDQ 16
#define NTOT 1196
#define HALFK 598
#define CH 128
#define QROWS 16

// ---------------- Kernel W: transpose Wq and MC (128x128 each) ----------------
__global__ __launch_bounds__(256) void k_wt(const float* __restrict__ Wq,
                                            const float* __restrict__ MC,
                                            float* __restrict__ WqT,
                                            float* __restrict__ MCT) {
  int r = blockIdx.x;            // output row (d)
  int t = threadIdx.x;
  int j = t & 127;
  if (t < 128) WqT[r * DD + j] = Wq[j * DD + r];
  else         MCT[r * DD + j] = MC[j * DD + r];
}

// ---------------- Kernel A: q = q_first + x @ Wq^T (LDS-staged W^T GEMM) ------
__global__ __launch_bounds__(256) void k_qcalc(const float* __restrict__ x,
                                               const float* __restrict__ WqT,
                                               const float* __restrict__ qf,
                                               float* __restrict__ qout) {
  __shared__ float sw[64 * DD];        // 32 KB: one d-half of W^T
  __shared__ float xs[QROWS * DD];     // 8 KB
  int tid = threadIdx.x;
  int row0 = blockIdx.x * QROWS;

  for (int i = tid; i < QROWS * DD / 4; i += 256)
    ((float4*)xs)[i] = ((const float4*)(x + (size_t)row0 * DD))[i];

  int j = tid & 127, rr = tid >> 7;
  float acc[8];
#pragma unroll
  for (int i = 0; i < 8; ++i) acc[i] = 0.f;

  for (int half = 0; half < 2; ++half) {
    __syncthreads();
    for (int i = tid; i < 64 * DD / 4; i += 256)
      ((float4*)sw)[i] = ((const float4*)(WqT + half * 64 * DD))[i];
    __syncthreads();
#pragma unroll
    for (int ri = 0; ri < 8; ++ri) {
      int r = 2 * ri + rr;
      float a = acc[ri];
#pragma unroll 16
      for (int d = 0; d < 64; ++d)
        a += xs[r * DD + half * 64 + d] * sw[d * DD + j];
      acc[ri] = a;
    }
  }
#pragma unroll
  for (int ri = 0; ri < 8; ++ri) {
    int bp = row0 + 2 * ri + rr;
    int b = bp / PP, p = bp % PP;
    int h = j >> 4, qd = j & 15;
    size_t qi = ((size_t)(b * HH + h) * PP + p) * QDQ + qd;
    qout[qi] = acc[ri] + qf[qi];
  }
}

// ---------------- Kernel F: mask transpose+pad (B,P,N) -> (B,NTOT,128) --------
__global__ __launch_bounds__(256) void k_mask_t(const float* __restrict__ mask,
                                                float* __restrict__ mt) {
  __shared__ float tile[64][65];
  int nt = blockIdx.x;           // 19 tiles over n (0..1215, pad to NTOT)
  int pt = blockIdx.y;           // 2 tiles over p (0..127)
  int b  = blockIdx.z;
  int tx = threadIdx.x & 63, ty = threadIdx.x >> 6;
  int n0 = nt * 64, p0 = pt * 64;
#pragma unroll
  for (int r = ty; r < 64; r += 4) {
    int p = p0 + r, n = n0 + tx;
    tile[r][tx] = (p < PP && n < NN) ? mask[((size_t)b * PP + p) * NN + n] : 0.f;
  }
  __syncthreads();
#pragma unroll
  for (int r = ty; r < 64; r += 4) {
    int n = n0 + r, p = p0 + tx;
    if (n < NTOT) mt[((size_t)b * NTOT + n) * 128 + p] = tile[tx][r];
  }
}

// ---------------- Kernel B: MHA partial, double-buffered LDS k/v --------------
// grid = 1024 (XCD-swizzled over 512 bh * 2 halves); block = 512
__global__ __launch_bounds__(512) void k_mha(const float* __restrict__ kk,
                                             const float* __restrict__ vv,
                                             const float* __restrict__ qws,
                                             const float* __restrict__ mt,
                                             float* __restrict__ part) {
  int bid = blockIdx.x;
  int swz = (bid & 7) * 128 + (bid >> 3);      // 16 blocks of same b per XCD
  int bh = swz >> 1, half = swz & 1;
  int b = bh >> 3;
  int tid = threadIdx.x;
  int g = tid >> 7;           // key-group 0..3
  int p = tid & 127;          // lane-query
  int pc = p < PP ? p : PP - 1;

  __shared__ __align__(16) float4 s4[2048];    // 32 KB: [buf][k|v][512]

  float q[QDQ];
  const float* qrow = qws + ((size_t)bh * PP + pc) * QDQ;
#pragma unroll
  for (int jj = 0; jj < QDQ; jj += 4) {
    float4 q4 = *(const float4*)(qrow + jj);
    q[jj] = q4.x * 0.25f; q[jj + 1] = q4.y * 0.25f;
    q[jj + 2] = q4.z * 0.25f; q[jj + 3] = q4.w * 0.25f;
  }

  float acc[QDQ];
#pragma unroll
  for (int jj = 0; jj < QDQ; ++jj) acc[jj] = 0.f;
  float m = -1e30f, l = 0.f;

  const float4* kg4 = (const float4*)(kk + (size_t)bh * NTOT * QDQ);
  const float4* vg4 = (const float4*)(vv + (size_t)bh * NTOT * QDQ);
  int key0 = half * HALFK;
  int gbase = key0 * 4;                        // float4 index of half start
  int lim = NTOT * 4 - 1;

  float4 rk, rv;
  { int gi = gbase + tid; gi = gi < lim ? gi : lim; rk = kg4[gi]; rv = vg4[gi]; }

  int cur = 0;
  for (int c = 0; c < 5; ++c) {                // 598 = 4*128 + 86
    int base = c * CH;
    int L = HALFK - base; if (L > CH) L = CH;
    __syncthreads();                           // buf[cur] free
    s4[cur * 1024 + tid] = rk;
    s4[cur * 1024 + 512 + tid] = rv;
    __syncthreads();
    if (c < 4) {                               // prefetch next chunk into regs
      int gi = gbase + (c + 1) * CH * 4 + tid; gi = gi < lim ? gi : lim;
      rk = kg4[gi]; rv = vg4[gi];
    }
    const float* mrow = mt + ((size_t)b * NTOT + key0 + base) * 128 + pc;
    int kb = cur * 1024, vb = cur * 1024 + 512;
#pragma unroll 2
    for (int i = g; i < L; i += 4) {
      float mk = mrow[i * 128];
      float4 k0 = s4[kb + i * 4 + 0], k1 = s4[kb + i * 4 + 1];
      float4 k2 = s4[kb + i * 4 + 2], k3 = s4[kb + i * 4 + 3];
      float sA = q[0] * k0.x + q[1] * k0.y + q[2] * k0.z + q[3] * k0.w;
      float sB = q[4] * k1.x + q[5] * k1.y + q[6] * k1.z + q[7] * k1.w;
      float sC = q[8] * k2.x + q[9] * k2.y + q[10] * k2.z + q[11] * k2.w;
      float sD = q[12] * k3.x + q[13] * k3.y + q[14] * k3.z + q[15] * k3.w;
      float s = (sA + sB) + (sC + sD) + mk;

      if (s > m + 8.f) {                       // deferred-max rescale (rare)
        float cc = __expf(m - s);
        l *= cc;
#pragma unroll
        for (int jj = 0; jj < QDQ; ++jj) acc[jj] *= cc;
        m = s;
      }
      float w = __expf(s - m);
      l += w;
      float4 v0 = s4[vb + i * 4 + 0], v1 = s4[vb + i * 4 + 1];
      float4 v2 = s4[vb + i * 4 + 2], v3 = s4[vb + i * 4 + 3];
      acc[0] += w * v0.x;  acc[1] += w * v0.y;  acc[2] += w * v0.z;  acc[3] += w * v0.w;
      acc[4] += w * v1.x;  acc[5] += w * v1.y;  acc[6] += w * v1.z;  acc[7] += w * v1.w;
      acc[8] += w * v2.x;  acc[9] += w * v2.y;  acc[10] += w * v2.z; acc[11] += w * v2.w;
      acc[12] += w * v3.x; acc[13] += w * v3.y; acc[14] += w * v3.z; acc[15] += w * v3.w;
    }
    cur ^= 1;
  }

  __syncthreads();                             // reuse smem for 4-way merge
  float* sm = (float*)s4;
  if (p < PP) {
    float* pl = sm + ((size_t)(g * PP + p)) * 18;
#pragma unroll
    for (int jj = 0; jj < QDQ; ++jj) pl[jj] = acc[jj];
    pl[16] = m;
    pl[17] = l;
  }
  __syncthreads();
  for (int idx = tid; idx < PP * QDQ; idx += 512) {
    int pp2 = idx >> 4, qd = idx & 15;
    float m0 = sm[(0 * PP + pp2) * 18 + 16], l0 = sm[(0 * PP + pp2) * 18 + 17];
    float m1 = sm[(1 * PP + pp2) * 18 + 16], l1 = sm[(1 * PP + pp2) * 18 + 17];
    float m2 = sm[(2 * PP + pp2) * 18 + 16], l2 = sm[(2 * PP + pp2) * 18 + 17];
    float m3 = sm[(3 * PP + pp2) * 18 + 16], l3 = sm[(3 * PP + pp2) * 18 + 17];
    float M = fmaxf(fmaxf(m0, m1), fmaxf(m2, m3));
    float c0 = __expf(m0 - M), c1 = __expf(m1 - M);
    float c2 = __expf(m2 - M), c3 = __expf(m3 - M);
    float A = sm[(0 * PP + pp2) * 18 + qd] * c0 + sm[(1 * PP + pp2) * 18 + qd] * c1
            + sm[(2 * PP + pp2) * 18 + qd] * c2 + sm[(3 * PP + pp2) * 18 + qd] * c3;
    float* o = part + ((size_t)swz * PP + pp2) * 18;
    o[qd] = A;
    if (qd == 0) {
      o[16] = M;
      o[17] = l0 * c0 + l1 * c1 + l2 * c2 + l3 * c3;
    }
  }
}

// ---------------- Kernel C: merge halves + mh_combine (LDS W^T GEMM) ----------
__global__ __launch_bounds__(256) void k_combine(const float* __restrict__ part,
                                                 const float* __restrict__ MCT,
                                                 float* __restrict__ mh) {
  __shared__ float sw[64 * DD];        // 32 KB
  __shared__ float oc[QROWS * DD];     // 8 KB
  int tid = threadIdx.x;
  int row0 = blockIdx.x * QROWS;

  for (int i = tid; i < QROWS * DD; i += 256) {
    int r = i >> 7, t = i & 127;
    int bp = row0 + r, b = bp / PP, p = bp % PP;
    int qd = t & 15, h = t >> 4;
    int bh = b * HH + h;
    const float* r0 = part + ((size_t)(bh * 2 + 0) * PP + p) * 18;
    const float* r1 = part + ((size_t)(bh * 2 + 1) * PP + p) * 18;
    float m0 = r0[16], l0 = r0[17], m1 = r1[16], l1 = r1[17];
    float M = fmaxf(m0, m1);
    float c0 = __expf(m0 - M), c1 = __expf(m1 - M);
    float L = l0 * c0 + l1 * c1;
    oc[i] = (r0[qd] * c0 + r1[qd] * c1) / L;
  }

  int j = tid & 127, rr = tid >> 7;
  float acc[8];
#pragma unroll
  for (int i = 0; i < 8; ++i) acc[i] = 0.f;

  for (int half = 0; half < 2; ++half) {
    __syncthreads();
    for (int i = tid; i < 64 * DD / 4; i += 256)
      ((float4*)sw)[i] = ((const float4*)(MCT + half * 64 * DD))[i];
    __syncthreads();
#pragma unroll
    for (int ri = 0; ri < 8; ++ri) {
      int r = 2 * ri + rr;
      float a = acc[ri];
#pragma unroll 16
      for (int d = 0; d < 64; ++d)
        a += oc[r * DD + half * 64 + d] * sw[d * DD + j];
      acc[ri] = a;
    }
  }
#pragma unroll
  for (int ri = 0; ri < 8; ++ri) {
    int bp = row0 + 2 * ri + rr;
    mh[(size_t)bp * DD + j] = acc[ri];
  }
}

// ---------------- Kernel D: score2[b,p,n] = sum_d mh[b,p,d]*shk[b,d,n] --------
__global__ __launch_bounds__(256) void k_score2(const float* __restrict__ mh,
                                                const float* __restrict__ shk,
                                                float* __restrict__ sc) {
  int bid = blockIdx.x;
  int swz = (bid & 7) * 128 + (bid >> 3);      // same-b blocks share an XCD
  int b = swz >> 4, nt = swz & 15;
  int tid = threadIdx.x; int nl = tid & 31, pg = tid >> 5;
  __shared__ float A[PP * 132];
  for (int idx = tid; idx < PP * DD; idx += 256)
    A[(idx >> 7) * 132 + (idx & 127)] = mh[(size_t)b * PP * DD + idx];
  __syncthreads();

  int na = nt * 64 + nl, nb2 = na + 32;
  int nca = na < NN ? na : NN - 1, ncb = nb2 < NN ? nb2 : NN - 1;
  const float* S = shk + (size_t)b * DD * NN;
  float acc0[13], acc1[13];
#pragma unroll
  for (int i = 0; i < 13; ++i) { acc0[i] = 0.f; acc1[i] = 0.f; }

  for (int d = 0; d < DD; d += 4) {
    float sa0 = S[(size_t)(d + 0) * NN + nca];
    float sa1 = S[(size_t)(d + 1) * NN + nca];
    float sa2 = S[(size_t)(d + 2) * NN + nca];
    float sa3 = S[(size_t)(d + 3) * NN + nca];
    float sb0 = S[(size_t)(d + 0) * NN + ncb];
    float sb1 = S[(size_t)(d + 1) * NN + ncb];
    float sb2 = S[(size_t)(d + 2) * NN + ncb];
    float sb3 = S[(size_t)(d + 3) * NN + ncb];
#pragma unroll
    for (int i = 0; i < 13; ++i) {
      int p = pg + (i << 3);
      if (p < PP) {
        const float4 a4 = *(const float4*)&A[p * 132 + d];
        acc0[i] += a4.x * sa0 + a4.y * sa1 + a4.z * sa2 + a4.w * sa3;
        acc1[i] += a4.x * sb0 + a4.y * sb1 + a4.z * sb2 + a4.w * sb3;
      }
    }
  }
#pragma unroll
  for (int i = 0; i < 13; ++i) {
    int p = pg + (i << 3);
    if (p < PP) {
      size_t base = ((size_t)b * PP + p) * NN;
      if (na < NN) sc[base + na] = acc0[i];
      if (nb2 < NN) sc[base + nb2] = acc1[i];
    }
  }
}

// ---------------- Kernel E: fast-tanh clip + edge bias + mask + row softmax ---
__global__ __launch_bounds__(256) void k_finsm(const float* __restrict__ sc,
                                               const float* __restrict__ eb,
                                               const int* __restrict__ cn,
                                               const float* __restrict__ mask,
                                               float* __restrict__ out) {
  int bid = blockIdx.x;
  int bp = (bid & 7) * 800 + (bid >> 3);       // XCD swizzle (6400 % 8 == 0)
  int b = bp / PP;
  int t = threadIdx.x;
  int node = cn[bp];
  const float* scp = sc + (size_t)bp * NN;
  const float* ebp = eb + ((size_t)b * NN + node) * NN;
  const float* mp = mask + (size_t)bp * NN;
  const float inv_sqrtD = 0.08838834764831845f;  // 1/sqrt(128)

  float vals[4];
  float m = -1e30f;
#pragma unroll
  for (int i = 0; i < 4; ++i) {
    int n = t + (i << 8);
    if (n < NN) {
      float z = scp[n] * inv_sqrtD;
      float e = __expf(2.f * z);
      float th10 = 10.f - 20.f * __builtin_amdgcn_rcpf(e + 1.f);  // 10*tanh(z)
      float lg = th10 + ebp[n] + mp[n];
      vals[i] = lg;
      m = fmaxf(m, lg);
    } else {
      vals[i] = -1e30f;
    }
  }
#pragma unroll
  for (int off = 32; off; off >>= 1) m = fmaxf(m, __shfl_xor(m, off));
  __shared__ float red[4];
  int w = t >> 6, lane = t & 63;
  if (lane == 0) red[w] = m;
  __syncthreads();
  m = fmaxf(fmaxf(red[0], red[1]), fmaxf(red[2], red[3]));
  __syncthreads();

  float s = 0.f;
#pragma unroll
  for (int i = 0; i < 4; ++i) {
    int n = t + (i << 8);
    float e = (n < NN) ? __expf(vals[i] - m) : 0.f;
    vals[i] = e;
    s += e;
  }
#pragma unroll
  for (int off = 32; off; off >>= 1) s += __shfl_xor(s, off);
  if (lane == 0) red[w] = s;
  __syncthreads();
  s = red[0] + red[1] + red[2] + red[3];
  float inv = 1.f / s;
#pragma unroll
  for (int i = 0; i < 4; ++i) {
    int n = t + (i << 8);
    if (n < NN) out[(size_t)bp * NN + n] = vals[i] * inv;
  }
}

extern "C" void kernel_launch(void* const* d_in, const int* in_sizes, int n_in,
                              void* d_out, int out_size, void* d_ws, size_t ws_size,
                              hipStream_t stream) {
  const float* x    = (const float*)d_in[0];   // encoded_last_node (B,P,D)
  const float* mask = (const float*)d_in[1];   // ninf_mask (B,P,N)
  const float* qf   = (const float*)d_in[2];   // q_first (B,H,P,QD)
  const float* kk   = (const float*)d_in[3];   // k (B,H,NTOT,QD)
  const float* vv   = (const float*)d_in[4];   // v (B,H,NTOT,QD)
  const float* shk  = (const float*)d_in[5];   // single_head_key (B,D,N)
  const float* Wq   = (const float*)d_in[6];   // (128,128)
  const float* MC   = (const float*)d_in[7];   // (128,128)
  const float* eb   = (const float*)d_in[8];   // edge_bias (B,N,N)
  const int*   cn   = (const int*)d_in[9];     // current_node (B,P)

  float* out = (float*)d_out;
  float* ws = (float*)d_ws;
  float* q_ws = ws;                                   //   819,200 f
  float* part = ws + 819200;                          // 1,843,200 f
  float* mh   = ws + 819200 + 1843200;                //   819,200 f
  float* mt   = ws + 819200 + 1843200 + 819200;       // 9,797,632 f (B*NTOT*128)
  float* sc   = mt;  // score2 overlays mt (written only after last mt read)
  float* wqt  = ws + 819200 + 1843200 + 819200 + 9797632;  // 16,384 f
  float* mct  = wqt + 16384;                                // 16,384 f

  hipLaunchKernelGGL(k_wt, dim3(128), dim3(256), 0, stream, Wq, MC, wqt, mct);
  hipLaunchKernelGGL(k_qcalc, dim3(400), dim3(256), 0, stream, x, wqt, qf, q_ws);
  hipLaunchKernelGGL(k_mask_t, dim3(19, 2, BB), dim3(256), 0, stream, mask, mt);
  hipLaunchKernelGGL(k_mha, dim3(1024), dim3(512), 0, stream, kk, vv, q_ws, mt, part);
  hipLaunchKernelGGL(k_combine, dim3(400), dim3(256), 0, stream, part, mct, mh);
  hipLaunchKernelGGL(k_score2, dim3(1024), dim3(256), 0, stream, mh, shk, sc);
  hipLaunchKernelGGL(k_finsm, dim3(6400), dim3(256), 0, stream, sc, eb, cn, mask, out);
}